// Round 14
// baseline (57.621 us; speedup 1.0000x reference)
//
#include <hip/hip_runtime.h>

#define NN 400
#define FF 240
#define CC 32
#define NIN 304   // F + 2C
#define LL 1440

// ---------------------------------------------------------------------------
// K1: P/Q projection, 4 rows per block (sw read once per 4 rows).
// grid = 100 blocks, 256 threads.  (R13 version, proven)
// ---------------------------------------------------------------------------
__global__ __launch_bounds__(256) void pq_kernel(
    const float* __restrict__ x, const float* __restrict__ sw,
    const float* __restrict__ sb, float* __restrict__ P, float* __restrict__ Q) {
    const int i0  = blockIdx.x * 4;
    const int t   = threadIdx.x;
    const int c   = t & 31;
    const int isQ = (t >> 5) & 1;
    const int g   = t >> 6;            // 0..3, 60 f each
    const float* wb = sw + (isQ ? FF * CC : 0) + c;
    const float bias = (!isQ && g == 0) ? sb[c] : 0.0f;
    float acc0 = bias, acc1 = bias, acc2 = bias, acc3 = bias;
    const float* xr = x + i0 * FF;
    const int f0 = g * 60;
    #pragma unroll 4
    for (int f = f0; f < f0 + 60; ++f) {
        const float w = wb[f * CC];
        acc0 += xr[f] * w;
        acc1 += xr[FF + f] * w;
        acc2 += xr[2 * FF + f] * w;
        acc3 += xr[3 * FF + f] * w;
    }
    __shared__ float red[4][256];
    const int slot = t & 63;
    red[g][slot]       = acc0;
    red[g][64 + slot]  = acc1;
    red[g][128 + slot] = acc2;
    red[g][192 + slot] = acc3;
    __syncthreads();
    {
        const int row = t >> 6, s2 = t & 63;
        const float s = red[0][row * 64 + s2] + red[1][row * 64 + s2]
                      + red[2][row * 64 + s2] + red[3][row * 64 + s2];
        const int i = i0 + row;
        if (s2 >= 32) Q[i * CC + (s2 & 31)] = s;
        else          P[i * CC + s2] = s;
    }
}

// ---------------------------------------------------------------------------
// K2/K3: one 1024-thread block per TWO rows (base, base+1; base even).
// XCD-swizzled. MERGED k-loop: one pass over all 400 k computes BOTH rows,
// so the Qk/Pk panel streams once per block (halved L2 traffic vs R13's two
// sequential row-phases) and the column gathers e/a[k][base..base+1] are one
// shared float2 per k. unroll 2 keeps live VGPR under the 128 cap that
// 16 waves/CU needs. Reductions run sequentially (row A, then row B).
// Then ONE node tail + ONE PQ tail for both rows.
// pg = t>>3 pair-group in [0,128), l = t&7 channel quad.
// ---------------------------------------------------------------------------
template<bool WRITE_E, bool DO_PQ>
__global__ __launch_bounds__(1024) void rcf_node(
    const float* __restrict__ P, const float* __restrict__ Q,
    const float* __restrict__ e, const float* __restrict__ a,
    const float* __restrict__ sw_tail,   // sw + 480*CC : rows [w1 ; w2]
    const float* __restrict__ aiw, const float* __restrict__ aib,
    const float* __restrict__ ajw, const float* __restrict__ ajb,
    const float* __restrict__ ew, const float* __restrict__ eb,
    float* __restrict__ e_out,
    const float* __restrict__ xin, const float* __restrict__ nw,
    const float* __restrict__ nb,
    const float* __restrict__ sw2, const float* __restrict__ sb2,
    float* __restrict__ xout, float* __restrict__ Pout, float* __restrict__ Qout) {
    const int bid  = blockIdx.x;
    const int base = (bid & 7) * 50 + (bid >> 3) * 2;   // even
    const int t  = threadIdx.x;
    const int pg = t >> 3, l = t & 7, c0 = l * 4;

    __shared__ float smem[10816];
    float* red  = smem;           // 9216 = 256*36 (rcf reduce; overlaid later)
    float* vA   = smem + 9216;    // 304
    float* vB   = smem + 9520;    // 304
    float* xsA  = smem + 9824;    // 240
    float* xsB  = smem + 10064;   // 240
    float* part = smem + 10304;   // 512
    float* redn = smem;           // 2*16*240 = 7680 (overlays red)
    float* red2 = smem;           // 2*16*64  = 2048 (overlays red)

    if (t < FF) {                 // stage both x-rows early
        vA[t] = xin[base * FF + t];
        vB[t] = xin[(base + 1) * FF + t];
    }

    // weights shared across both rows
    float w1v[4], w2v[4], wiv[4], wjv[4], wev[4];
    *(float4*)w1v = *(const float4*)(sw_tail + c0);
    *(float4*)w2v = *(const float4*)(sw_tail + CC + c0);
    *(float4*)wiv = *(const float4*)(aiw + c0);
    *(float4*)wjv = *(const float4*)(ajw + c0);
    if (WRITE_E) *(float4*)wev = *(const float4*)(ew + c0);
    const float bi = aib[0], bj = ajb[0];
    const float be = WRITE_E ? eb[0] : 0.0f;

    float PbA[4], QbA[4], PbB[4], QbB[4];
    *(float4*)PbA = *(const float4*)(P + base * CC + c0);
    *(float4*)QbA = *(const float4*)(Q + base * CC + c0);
    *(float4*)PbB = *(const float4*)(P + (base + 1) * CC + c0);
    *(float4*)QbB = *(const float4*)(Q + (base + 1) * CC + c0);

    float acciA[4] = {0, 0, 0, 0}, accjA[4] = {0, 0, 0, 0};
    float acciB[4] = {0, 0, 0, 0}, accjB[4] = {0, 0, 0, 0};

    #pragma unroll 2
    for (int it = 0; it < 4; ++it) {
        const int off = it * 128 + pg;
        const bool valid = off < NN;
        const int k = valid ? off : 0;
        float Qk[4], Pk[4];
        *(float4*)Qk = *(const float4*)(Q + k * CC + c0);   // shared by rows
        *(float4*)Pk = *(const float4*)(P + k * CC + c0);   // shared by rows
        const float2 er = *(const float2*)(e + k * NN + base);  // shared gather
        const float2 ak = *(const float2*)(a + k * NN + base);  // shared gather
        const float e_fA  = e[base * NN + k];
        const float e_fB  = e[(base + 1) * NN + k];
        const float a_bkA = a[base * NN + k];
        const float a_bkB = a[(base + 1) * NN + k];

        // ---- row A ----
        {
            float sr[4], sc[4];
            #pragma unroll
            for (int q = 0; q < 4; ++q) {
                sr[q] = fmaxf(PbA[q] + Qk[q] + e_fA * w1v[q] + er.x * w2v[q], 0.0f) * a_bkA;
                sc[q] = fmaxf(Pk[q] + QbA[q] + er.x * w1v[q] + e_fA * w2v[q], 0.0f) * ak.x;
            }
            float d_i = sr[0] * wiv[0] + sr[1] * wiv[1] + sr[2] * wiv[2] + sr[3] * wiv[3];
            float d_j = sc[0] * wjv[0] + sc[1] * wjv[1] + sc[2] * wjv[2] + sc[3] * wjv[3];
            float d_e = WRITE_E ? (sr[0] * wev[0] + sr[1] * wev[1] + sr[2] * wev[2] + sr[3] * wev[3]) : 0.0f;
            #pragma unroll
            for (int m = 1; m < 8; m <<= 1) {
                d_i += __shfl_xor(d_i, m);
                d_j += __shfl_xor(d_j, m);
                if (WRITE_E) d_e += __shfl_xor(d_e, m);
            }
            const float gi = valid ? __fdividef(1.0f, 1.0f + __expf(-(d_i + bi))) : 0.0f;
            const float gj = valid ? __fdividef(1.0f, 1.0f + __expf(-(d_j + bj))) : 0.0f;
            #pragma unroll
            for (int q = 0; q < 4; ++q) {
                acciA[q] += gi * sr[q];
                accjA[q] += gj * sc[q];
            }
            if (WRITE_E && l == 0 && valid) e_out[base * NN + k] = d_e + be;
        }
        // ---- row B ----
        {
            float sr[4], sc[4];
            #pragma unroll
            for (int q = 0; q < 4; ++q) {
                sr[q] = fmaxf(PbB[q] + Qk[q] + e_fB * w1v[q] + er.y * w2v[q], 0.0f) * a_bkB;
                sc[q] = fmaxf(Pk[q] + QbB[q] + er.y * w1v[q] + e_fB * w2v[q], 0.0f) * ak.y;
            }
            float d_i = sr[0] * wiv[0] + sr[1] * wiv[1] + sr[2] * wiv[2] + sr[3] * wiv[3];
            float d_j = sc[0] * wjv[0] + sc[1] * wjv[1] + sc[2] * wjv[2] + sc[3] * wjv[3];
            float d_e = WRITE_E ? (sr[0] * wev[0] + sr[1] * wev[1] + sr[2] * wev[2] + sr[3] * wev[3]) : 0.0f;
            #pragma unroll
            for (int m = 1; m < 8; m <<= 1) {
                d_i += __shfl_xor(d_i, m);
                d_j += __shfl_xor(d_j, m);
                if (WRITE_E) d_e += __shfl_xor(d_e, m);
            }
            const float gi = valid ? __fdividef(1.0f, 1.0f + __expf(-(d_i + bi))) : 0.0f;
            const float gj = valid ? __fdividef(1.0f, 1.0f + __expf(-(d_j + bj))) : 0.0f;
            #pragma unroll
            for (int q = 0; q < 4; ++q) {
                acciB[q] += gi * sr[q];
                accjB[q] += gj * sc[q];
            }
            if (WRITE_E && l == 0 && valid) e_out[(base + 1) * NN + k] = d_e + be;
        }
    }

    // ---- reductions: row A then row B (same LDS buffers) ----
    #pragma unroll
    for (int rp = 0; rp < 2; ++rp) {
        float* ai = rp ? acciB : acciA;
        float* aj = rp ? accjB : accjA;
        float* vcur = rp ? vB : vA;
        #pragma unroll
        for (int q = 0; q < 4; ++q) {
            red[pg * 36 + c0 + q]         = ai[q];
            red[(128 + pg) * 36 + c0 + q] = aj[q];
        }
        __syncthreads();
        if (t < 512) {   // stage-1: each sums 16 pair-groups
            const int c = t & 31, sg = (t >> 5) & 7, which = t >> 8;
            float s = 0.0f;
            #pragma unroll
            for (int g2 = sg * 16; g2 < sg * 16 + 16; ++g2)
                s += red[(which * 128 + g2) * 36 + c];
            part[t] = s;
        }
        __syncthreads();
        if (t < 64) {    // stage-2 into vcur[240+t]
            const int which = t >> 5, c = t & 31;
            float s = 0.0f;
            #pragma unroll
            for (int sg = 0; sg < 8; ++sg) s += part[which * 256 + sg * 32 + c];
            vcur[FF + t] = s;
        }
        __syncthreads();
    }

    // ---- node tail for BOTH rows: nw read once per block ----
    {
        const int fg = t % 60, h = t / 60;   // h in [0,16), 19 k each
        if (t < 960) {
            const int f0 = fg * 4;
            float4 aA = make_float4(0.f, 0.f, 0.f, 0.f);
            float4 aB = make_float4(0.f, 0.f, 0.f, 0.f);
            const int k0 = h * 19;
            #pragma unroll
            for (int k = k0; k < k0 + 19; ++k) {
                const float4 w = *(const float4*)(nw + k * FF + f0);
                const float va = vA[k], vb = vB[k];
                aA.x += va * w.x; aA.y += va * w.y; aA.z += va * w.z; aA.w += va * w.w;
                aB.x += vb * w.x; aB.y += vb * w.y; aB.z += vb * w.z; aB.w += vb * w.w;
            }
            *(float4*)(redn + h * 240 + f0)        = aA;
            *(float4*)(redn + 3840 + h * 240 + f0) = aB;
        }
    }
    __syncthreads();
    if (t < FF) {
        float rA = nb[t], rB = nb[t];
        #pragma unroll
        for (int h = 0; h < 16; ++h) {
            rA += redn[h * 240 + t];
            rB += redn[3840 + h * 240 + t];
        }
        xout[base * FF + t]       = rA;
        xout[(base + 1) * FF + t] = rB;
        xsA[t] = rA;
        xsB[t] = rB;
    }
    if (DO_PQ) {
        __syncthreads();
        const int c = t & 31, isQ = (t >> 5) & 1, g = t >> 6;   // g in [0,16)
        const float* wb = sw2 + (isQ ? FF * CC : 0) + c;
        const float bias = (!isQ && g == 0) ? sb2[c] : 0.0f;
        float accA = bias, accB = bias;
        const int f0 = g * 15;
        #pragma unroll
        for (int f = f0; f < f0 + 15; ++f) {
            const float w = wb[f * CC];
            accA += xsA[f] * w;
            accB += xsB[f] * w;
        }
        red2[g * 64 + (t & 63)]        = accA;
        red2[1024 + g * 64 + (t & 63)] = accB;
        __syncthreads();
        if (t < 128) {
            const int row = t >> 6, slot = t & 63;
            float s = 0.0f;
            #pragma unroll
            for (int g2 = 0; g2 < 16; ++g2) s += red2[row * 1024 + g2 * 64 + slot];
            const int bb = base + row;
            if (slot >= 32) Qout[bb * CC + (slot & 31)] = s;
            else            Pout[bb * CC + slot] = s;
        }
    }
}

// ---------------------------------------------------------------------------
// K4: in-block split-K dense (R13 version, proven). 1024 threads = 4 f-chunks
// x 256 l-lanes; 60 loads/thread; partials reduced through LDS.
// grid = (50, 6), block 1024.
// ---------------------------------------------------------------------------
__global__ __launch_bounds__(1024) void dense_kernel(
    const float* __restrict__ x, const float* __restrict__ dw,
    const float* __restrict__ db, float* __restrict__ out) {
    const int i0 = blockIdx.x * 8;
    const int t  = threadIdx.x;
    const int l  = t & 255;          // l-lane
    const int fs = t >> 8;           // f-chunk 0..3
    const int gl = blockIdx.y * 256 + l;
    __shared__ float xs[8 * FF];     // 1920
    __shared__ float red[32 * 256];  // 8192
    for (int idx = t; idx < 8 * FF; idx += 1024) {
        const int r = idx / FF, f = idx - r * FF;
        xs[r * FF + f] = x[(i0 + r) * FF + f];
    }
    __syncthreads();
    float acc[8] = {0, 0, 0, 0, 0, 0, 0, 0};
    if (gl < LL) {
        const int f0 = fs * 60;
        #pragma unroll 4
        for (int f = f0; f < f0 + 60; ++f) {
            const float w = dw[f * LL + gl];
            #pragma unroll
            for (int r = 0; r < 8; ++r) acc[r] += xs[r * FF + f] * w;
        }
    }
    #pragma unroll
    for (int r = 0; r < 8; ++r) red[(fs * 8 + r) * 256 + l] = acc[r];
    __syncthreads();
    if (gl < LL) {
        const int r2 = t >> 8;       // rows r2 and r2+4
        const float d = db[gl];
        #pragma unroll
        for (int rr = r2; rr < 8; rr += 4) {
            const float s = red[(0 + rr) * 256 + l] + red[(8 + rr) * 256 + l]
                          + red[(16 + rr) * 256 + l] + red[(24 + rr) * 256 + l];
            out[(i0 + rr) * LL + gl] = d + s;
        }
    }
}

extern "C" void kernel_launch(void* const* d_in, const int* in_sizes, int n_in,
                              void* d_out, int out_size, void* d_ws, size_t ws_size,
                              hipStream_t stream) {
    const float* x  = (const float*)d_in[0];
    const float* a  = (const float*)d_in[1];
    const float* e0 = (const float*)d_in[2];

    const float* c1_sw  = (const float*)d_in[3];
    const float* c1_sb  = (const float*)d_in[4];
    const float* c1_aiw = (const float*)d_in[5];
    const float* c1_aib = (const float*)d_in[6];
    const float* c1_ajw = (const float*)d_in[7];
    const float* c1_ajb = (const float*)d_in[8];
    const float* c1_nw  = (const float*)d_in[9];
    const float* c1_nb  = (const float*)d_in[10];
    const float* c1_ew  = (const float*)d_in[11];
    const float* c1_eb  = (const float*)d_in[12];

    const float* c2_sw  = (const float*)d_in[13];
    const float* c2_sb  = (const float*)d_in[14];
    const float* c2_aiw = (const float*)d_in[15];
    const float* c2_aib = (const float*)d_in[16];
    const float* c2_ajw = (const float*)d_in[17];
    const float* c2_ajb = (const float*)d_in[18];
    const float* c2_nw  = (const float*)d_in[19];
    const float* c2_nb  = (const float*)d_in[20];
    // d_in[21]/d_in[22] (c2_ew/c2_eb): layer-2 edge output is dead code
    const float* dw = (const float*)d_in[23];
    const float* db = (const float*)d_in[24];

    float* ws = (float*)d_ws;
    float* P1 = ws;                 // 12800
    float* Q1 = ws + 12800;         // 12800
    float* P2 = ws + 25600;         // 12800
    float* Q2 = ws + 38400;         // 12800
    float* x1 = ws + 51200;         // 96000
    float* x2 = ws + 147200;        // 96000
    float* e1 = ws + 243200;        // 160000

    float* out = (float*)d_out;

    // K1: layer-1 P/Q projection (4 rows/block)
    pq_kernel<<<NN / 4, 256, 0, stream>>>(x, c1_sw, c1_sb, P1, Q1);

    // K2: layer-1 rcf + node model + layer-2 P/Q (2 rows/block, merged k-loop)
    rcf_node<true, true><<<NN / 2, 1024, 0, stream>>>(
        P1, Q1, e0, a, c1_sw + 480 * CC,
        c1_aiw, c1_aib, c1_ajw, c1_ajb, c1_ew, c1_eb, e1,
        x, c1_nw, c1_nb, c2_sw, c2_sb, x1, P2, Q2);

    // K3: layer-2 rcf + node model (no e_out, no next PQ)
    rcf_node<false, false><<<NN / 2, 1024, 0, stream>>>(
        P2, Q2, e1, a, c2_sw + 480 * CC,
        c2_aiw, c2_aib, c2_ajw, c2_ajb, nullptr, nullptr, nullptr,
        x1, c2_nw, c2_nb, nullptr, nullptr, x2, nullptr, nullptr);

    // K4: final dense (in-block split-K)
    dense_kernel<<<dim3(NN / 8, 6), 1024, 0, stream>>>(x2, dw, db, out);
}

// Round 15
// 51.916 us; speedup vs baseline: 1.1099x; 1.1099x over previous
//
#include <hip/hip_runtime.h>

#define NN 400
#define FF 240
#define CC 32
#define NIN 304   // F + 2C
#define LL 1440

// ---------------------------------------------------------------------------
// K1: P/Q projection, 4 rows per block (sw read once per 4 rows).
// grid = 100 blocks, 256 threads.  (proven)
// ---------------------------------------------------------------------------
__global__ __launch_bounds__(256) void pq_kernel(
    const float* __restrict__ x, const float* __restrict__ sw,
    const float* __restrict__ sb, float* __restrict__ P, float* __restrict__ Q) {
    const int i0  = blockIdx.x * 4;
    const int t   = threadIdx.x;
    const int c   = t & 31;
    const int isQ = (t >> 5) & 1;
    const int g   = t >> 6;            // 0..3, 60 f each
    const float* wb = sw + (isQ ? FF * CC : 0) + c;
    const float bias = (!isQ && g == 0) ? sb[c] : 0.0f;
    float acc0 = bias, acc1 = bias, acc2 = bias, acc3 = bias;
    const float* xr = x + i0 * FF;
    const int f0 = g * 60;
    #pragma unroll 4
    for (int f = f0; f < f0 + 60; ++f) {
        const float w = wb[f * CC];
        acc0 += xr[f] * w;
        acc1 += xr[FF + f] * w;
        acc2 += xr[2 * FF + f] * w;
        acc3 += xr[3 * FF + f] * w;
    }
    __shared__ float red[4][256];
    const int slot = t & 63;
    red[g][slot]       = acc0;
    red[g][64 + slot]  = acc1;
    red[g][128 + slot] = acc2;
    red[g][192 + slot] = acc3;
    __syncthreads();
    {
        const int row = t >> 6, s2 = t & 63;
        const float s = red[0][row * 64 + s2] + red[1][row * 64 + s2]
                      + red[2][row * 64 + s2] + red[3][row * 64 + s2];
        const int i = i0 + row;
        if (s2 >= 32) Q[i * CC + (s2 & 31)] = s;
        else          P[i * CC + s2] = s;
    }
}

// ---------------------------------------------------------------------------
// K2/K3: R13 structure (two sequential row-phases, shared float2 column
// gathers) + LDS-STAGED P/Q PANEL: the 102.4 KB panel is copied to LDS once
// (coalesced), so the k-loop's Qk/Pk reads are ds_read_b128 at ~0 latency
// (each wave reads 1024 contiguous LDS bytes -> conflict-free) instead of
// L2-latency-exposed VMEM. e_out staged in LDS -> one coalesced 800-float
// store (rows base/base+1 adjacent). LDS 148.9 KB, 1 block/CU (as before).
// pg = t>>3 pair-group in [0,128), l = t&7 channel quad.
// ---------------------------------------------------------------------------
template<bool WRITE_E, bool DO_PQ>
__global__ __launch_bounds__(1024) void rcf_node(
    const float* __restrict__ P, const float* __restrict__ Q,
    const float* __restrict__ e, const float* __restrict__ a,
    const float* __restrict__ sw_tail,   // sw + 480*CC : rows [w1 ; w2]
    const float* __restrict__ aiw, const float* __restrict__ aib,
    const float* __restrict__ ajw, const float* __restrict__ ajb,
    const float* __restrict__ ew, const float* __restrict__ eb,
    float* __restrict__ e_out,
    const float* __restrict__ xin, const float* __restrict__ nw,
    const float* __restrict__ nb,
    const float* __restrict__ sw2, const float* __restrict__ sb2,
    float* __restrict__ xout, float* __restrict__ Pout, float* __restrict__ Qout) {
    const int bid  = blockIdx.x;
    const int base = (bid & 7) * 50 + (bid >> 3) * 2;   // even
    const int t  = threadIdx.x;
    const int pg = t >> 3, l = t & 7, c0 = l * 4;

    __shared__ float smem[10816];
    __shared__ float LP[NN * CC];     // 51.2 KB  P panel
    __shared__ float LQ[NN * CC];     // 51.2 KB  Q panel
    __shared__ float eout_lds[2 * NN];
    float* red  = smem;           // 9216 = 256*36 (rcf reduce; overlaid later)
    float* vA   = smem + 9216;    // 304
    float* vB   = smem + 9520;    // 304
    float* xsA  = smem + 9824;    // 240
    float* xsB  = smem + 10064;   // 240
    float* part = smem + 10304;   // 512
    float* redn = smem;           // 2*16*240 = 7680 (overlays red)
    float* red2 = smem;           // 2*16*64  = 2048 (overlays red)

    if (t < FF) {                 // stage both x-rows early
        vA[t] = xin[base * FF + t];
        vB[t] = xin[(base + 1) * FF + t];
    }
    // stage P/Q panel into LDS (coalesced float4, 4 iterations)
    for (int idx = t; idx < NN * CC / 4; idx += 1024) {
        ((float4*)LP)[idx] = ((const float4*)P)[idx];
        ((float4*)LQ)[idx] = ((const float4*)Q)[idx];
    }

    // hoisted SHARED column gathers (one float2 line serves both rows)
    float2 er2[4], ak2[4];
    int kk[4];
    #pragma unroll
    for (int it = 0; it < 4; ++it) {
        const int off = it * 128 + pg;
        kk[it] = (off < NN) ? off : 0;
        er2[it] = *(const float2*)(e + kk[it] * NN + base);
        ak2[it] = *(const float2*)(a + kk[it] * NN + base);
    }

    float w1v[4], w2v[4], wiv[4], wjv[4], wev[4];
    *(float4*)w1v = *(const float4*)(sw_tail + c0);
    *(float4*)w2v = *(const float4*)(sw_tail + CC + c0);
    *(float4*)wiv = *(const float4*)(aiw + c0);
    *(float4*)wjv = *(const float4*)(ajw + c0);
    if (WRITE_E) *(float4*)wev = *(const float4*)(ew + c0);
    const float bi = aib[0], bj = ajb[0];
    const float be = WRITE_E ? eb[0] : 0.0f;

    __syncthreads();   // panel ready

    #pragma unroll
    for (int rp = 0; rp < 2; ++rp) {
        const int b = base + rp;
        float* vcur = rp ? vB : vA;

        float Pb[4], Qb[4];
        *(float4*)Pb = *(const float4*)(LP + b * CC + c0);
        *(float4*)Qb = *(const float4*)(LQ + b * CC + c0);

        float acc_i[4] = {0, 0, 0, 0}, acc_j[4] = {0, 0, 0, 0};
        #pragma unroll
        for (int it = 0; it < 4; ++it) {
            const int off = it * 128 + pg;
            const bool valid = off < NN;
            const int k = kk[it];
            float Qk[4], Pk[4];
            *(float4*)Qk = *(const float4*)(LQ + k * CC + c0);   // LDS, ~0 lat
            *(float4*)Pk = *(const float4*)(LP + k * CC + c0);   // LDS, ~0 lat
            const float e_f  = e[b * NN + k];                    // coalesced
            const float a_bk = a[b * NN + k];                    // coalesced
            const float e_r  = rp ? er2[it].y : er2[it].x;       // shared gather
            const float a_kb = rp ? ak2[it].y : ak2[it].x;       // shared gather
            float sr[4], sc[4];
            #pragma unroll
            for (int q = 0; q < 4; ++q) {
                sr[q] = fmaxf(Pb[q] + Qk[q] + e_f * w1v[q] + e_r * w2v[q], 0.0f) * a_bk;
                sc[q] = fmaxf(Pk[q] + Qb[q] + e_r * w1v[q] + e_f * w2v[q], 0.0f) * a_kb;
            }
            float d_i = sr[0] * wiv[0] + sr[1] * wiv[1] + sr[2] * wiv[2] + sr[3] * wiv[3];
            float d_j = sc[0] * wjv[0] + sc[1] * wjv[1] + sc[2] * wjv[2] + sc[3] * wjv[3];
            float d_e = WRITE_E ? (sr[0] * wev[0] + sr[1] * wev[1] + sr[2] * wev[2] + sr[3] * wev[3]) : 0.0f;
            #pragma unroll
            for (int m = 1; m < 8; m <<= 1) {
                d_i += __shfl_xor(d_i, m);
                d_j += __shfl_xor(d_j, m);
                if (WRITE_E) d_e += __shfl_xor(d_e, m);
            }
            const float gi = valid ? __fdividef(1.0f, 1.0f + __expf(-(d_i + bi))) : 0.0f;
            const float gj = valid ? __fdividef(1.0f, 1.0f + __expf(-(d_j + bj))) : 0.0f;
            #pragma unroll
            for (int q = 0; q < 4; ++q) {
                acc_i[q] += gi * sr[q];
                acc_j[q] += gj * sc[q];
            }
            if (WRITE_E && l == 0 && valid) eout_lds[rp * NN + k] = d_e + be;
        }
        #pragma unroll
        for (int q = 0; q < 4; ++q) {
            red[pg * 36 + c0 + q]          = acc_i[q];
            red[(128 + pg) * 36 + c0 + q]  = acc_j[q];
        }
        __syncthreads();
        if (t < 512) {   // stage-1: each sums 16 pair-groups
            const int c = t & 31, sg = (t >> 5) & 7, which = t >> 8;
            float s = 0.0f;
            #pragma unroll
            for (int g2 = sg * 16; g2 < sg * 16 + 16; ++g2)
                s += red[(which * 128 + g2) * 36 + c];
            part[t] = s;
        }
        __syncthreads();
        if (t < 64) {    // stage-2 into vcur[240+t]
            const int which = t >> 5, c = t & 31;
            float s = 0.0f;
            #pragma unroll
            for (int sg = 0; sg < 8; ++sg) s += part[which * 256 + sg * 32 + c];
            vcur[FF + t] = s;
        }
        __syncthreads();
    }

    // coalesced e_out store: rows base, base+1 are contiguous in memory
    if (WRITE_E && t < 2 * NN) e_out[base * NN + t] = eout_lds[t];

    // ---- node tail for BOTH rows: nw read once per block ----
    {
        const int fg = t % 60, h = t / 60;   // h in [0,16), 19 k each
        if (t < 960) {
            const int f0 = fg * 4;
            float4 aA = make_float4(0.f, 0.f, 0.f, 0.f);
            float4 aB = make_float4(0.f, 0.f, 0.f, 0.f);
            const int k0 = h * 19;
            #pragma unroll
            for (int k = k0; k < k0 + 19; ++k) {
                const float4 w = *(const float4*)(nw + k * FF + f0);
                const float va = vA[k], vb = vB[k];
                aA.x += va * w.x; aA.y += va * w.y; aA.z += va * w.z; aA.w += va * w.w;
                aB.x += vb * w.x; aB.y += vb * w.y; aB.z += vb * w.z; aB.w += vb * w.w;
            }
            *(float4*)(redn + h * 240 + f0)        = aA;
            *(float4*)(redn + 3840 + h * 240 + f0) = aB;
        }
    }
    __syncthreads();
    if (t < FF) {
        float rA = nb[t], rB = nb[t];
        #pragma unroll
        for (int h = 0; h < 16; ++h) {
            rA += redn[h * 240 + t];
            rB += redn[3840 + h * 240 + t];
        }
        xout[base * FF + t]       = rA;
        xout[(base + 1) * FF + t] = rB;
        xsA[t] = rA;
        xsB[t] = rB;
    }
    if (DO_PQ) {
        __syncthreads();
        const int c = t & 31, isQ = (t >> 5) & 1, g = t >> 6;   // g in [0,16)
        const float* wb = sw2 + (isQ ? FF * CC : 0) + c;
        const float bias = (!isQ && g == 0) ? sb2[c] : 0.0f;
        float accA = bias, accB = bias;
        const int f0 = g * 15;
        #pragma unroll
        for (int f = f0; f < f0 + 15; ++f) {
            const float w = wb[f * CC];
            accA += xsA[f] * w;
            accB += xsB[f] * w;
        }
        red2[g * 64 + (t & 63)]        = accA;
        red2[1024 + g * 64 + (t & 63)] = accB;
        __syncthreads();
        if (t < 128) {
            const int row = t >> 6, slot = t & 63;
            float s = 0.0f;
            #pragma unroll
            for (int g2 = 0; g2 < 16; ++g2) s += red2[row * 1024 + g2 * 64 + slot];
            const int bb = base + row;
            if (slot >= 32) Qout[bb * CC + (slot & 31)] = s;
            else            Pout[bb * CC + slot] = s;
        }
    }
}

// ---------------------------------------------------------------------------
// K4: in-block split-K dense (proven). 1024 threads = 4 f-chunks x 256
// l-lanes; 60 loads/thread; partials reduced through LDS.
// grid = (50, 6), block 1024.
// ---------------------------------------------------------------------------
__global__ __launch_bounds__(1024) void dense_kernel(
    const float* __restrict__ x, const float* __restrict__ dw,
    const float* __restrict__ db, float* __restrict__ out) {
    const int i0 = blockIdx.x * 8;
    const int t  = threadIdx.x;
    const int l  = t & 255;          // l-lane
    const int fs = t >> 8;           // f-chunk 0..3
    const int gl = blockIdx.y * 256 + l;
    __shared__ float xs[8 * FF];     // 1920
    __shared__ float red[32 * 256];  // 8192
    for (int idx = t; idx < 8 * FF; idx += 1024) {
        const int r = idx / FF, f = idx - r * FF;
        xs[r * FF + f] = x[(i0 + r) * FF + f];
    }
    __syncthreads();
    float acc[8] = {0, 0, 0, 0, 0, 0, 0, 0};
    if (gl < LL) {
        const int f0 = fs * 60;
        #pragma unroll 4
        for (int f = f0; f < f0 + 60; ++f) {
            const float w = dw[f * LL + gl];
            #pragma unroll
            for (int r = 0; r < 8; ++r) acc[r] += xs[r * FF + f] * w;
        }
    }
    #pragma unroll
    for (int r = 0; r < 8; ++r) red[(fs * 8 + r) * 256 + l] = acc[r];
    __syncthreads();
    if (gl < LL) {
        const int r2 = t >> 8;       // rows r2 and r2+4
        const float d = db[gl];
        #pragma unroll
        for (int rr = r2; rr < 8; rr += 4) {
            const float s = red[(0 + rr) * 256 + l] + red[(8 + rr) * 256 + l]
                          + red[(16 + rr) * 256 + l] + red[(24 + rr) * 256 + l];
            out[(i0 + rr) * LL + gl] = d + s;
        }
    }
}

extern "C" void kernel_launch(void* const* d_in, const int* in_sizes, int n_in,
                              void* d_out, int out_size, void* d_ws, size_t ws_size,
                              hipStream_t stream) {
    const float* x  = (const float*)d_in[0];
    const float* a  = (const float*)d_in[1];
    const float* e0 = (const float*)d_in[2];

    const float* c1_sw  = (const float*)d_in[3];
    const float* c1_sb  = (const float*)d_in[4];
    const float* c1_aiw = (const float*)d_in[5];
    const float* c1_aib = (const float*)d_in[6];
    const float* c1_ajw = (const float*)d_in[7];
    const float* c1_ajb = (const float*)d_in[8];
    const float* c1_nw  = (const float*)d_in[9];
    const float* c1_nb  = (const float*)d_in[10];
    const float* c1_ew  = (const float*)d_in[11];
    const float* c1_eb  = (const float*)d_in[12];

    const float* c2_sw  = (const float*)d_in[13];
    const float* c2_sb  = (const float*)d_in[14];
    const float* c2_aiw = (const float*)d_in[15];
    const float* c2_aib = (const float*)d_in[16];
    const float* c2_ajw = (const float*)d_in[17];
    const float* c2_ajb = (const float*)d_in[18];
    const float* c2_nw  = (const float*)d_in[19];
    const float* c2_nb  = (const float*)d_in[20];
    // d_in[21]/d_in[22] (c2_ew/c2_eb): layer-2 edge output is dead code
    const float* dw = (const float*)d_in[23];
    const float* db = (const float*)d_in[24];

    float* ws = (float*)d_ws;
    float* P1 = ws;                 // 12800
    float* Q1 = ws + 12800;         // 12800
    float* P2 = ws + 25600;         // 12800
    float* Q2 = ws + 38400;         // 12800
    float* x1 = ws + 51200;         // 96000
    float* x2 = ws + 147200;        // 96000
    float* e1 = ws + 243200;        // 160000

    float* out = (float*)d_out;

    // K1: layer-1 P/Q projection (4 rows/block)
    pq_kernel<<<NN / 4, 256, 0, stream>>>(x, c1_sw, c1_sb, P1, Q1);

    // K2: layer-1 rcf + node model + layer-2 P/Q (LDS-staged panel)
    rcf_node<true, true><<<NN / 2, 1024, 0, stream>>>(
        P1, Q1, e0, a, c1_sw + 480 * CC,
        c1_aiw, c1_aib, c1_ajw, c1_ajb, c1_ew, c1_eb, e1,
        x, c1_nw, c1_nb, c2_sw, c2_sb, x1, P2, Q2);

    // K3: layer-2 rcf + node model (no e_out, no next PQ)
    rcf_node<false, false><<<NN / 2, 1024, 0, stream>>>(
        P2, Q2, e1, a, c2_sw + 480 * CC,
        c2_aiw, c2_aib, c2_ajw, c2_ajb, nullptr, nullptr, nullptr,
        x1, c2_nw, c2_nb, nullptr, nullptr, x2, nullptr, nullptr);

    // K4: final dense (in-block split-K)
    dense_kernel<<<dim3(NN / 8, 6), 1024, 0, stream>>>(x2, dw, db, out);
}

// Round 16
// 50.009 us; speedup vs baseline: 1.1522x; 1.0381x over previous
//
#include <hip/hip_runtime.h>

#define NN 400
#define FF 240
#define CC 32
#define NIN 304   // F + 2C
#define LL 1440

// ---------------------------------------------------------------------------
// K1: P/Q projection, 1 row per block (minimal serial latency; sw traffic
// proven irrelevant in R10). grid = 400 blocks, 256 threads.
// ---------------------------------------------------------------------------
__global__ __launch_bounds__(256) void pq_kernel(
    const float* __restrict__ x, const float* __restrict__ sw,
    const float* __restrict__ sb, float* __restrict__ P, float* __restrict__ Q) {
    const int i   = blockIdx.x;
    const int t   = threadIdx.x;
    const int c   = t & 31;
    const int isQ = (t >> 5) & 1;
    const int g   = t >> 6;            // 0..3, 60 f each
    const float* wb = sw + (isQ ? FF * CC : 0) + c;
    float acc = (!isQ && g == 0) ? sb[c] : 0.0f;
    const float* xr = x + i * FF;
    const int f0 = g * 60;
    #pragma unroll 4
    for (int f = f0; f < f0 + 60; ++f) acc += xr[f] * wb[f * CC];
    __shared__ float red[4][64];
    red[g][t & 63] = acc;
    __syncthreads();
    if (t < 64) {
        const float s = red[0][t] + red[1][t] + red[2][t] + red[3][t];
        if (t >= 32) Q[i * CC + (t & 31)] = s;
        else         P[i * CC + t] = s;
    }
}

// ---------------------------------------------------------------------------
// K2/K3: one 1024-thread block per TWO rows (base, base+1; base even),
// XCD-swizzled. R13 main-loop structure (two sequential row k-loops, global
// P/Q reads — proven latency-hidden; shared float2 column gathers), but the
// reductions are COMBINED: each row's accumulators are written to LDS right
// after its loop (no barrier needed for writes), then ONE sync -> ONE
// stage-1 over all 4 sets (1024 threads) -> sync -> stage-2 -> sync.
// 3 barriers instead of 6 in a 16-wave block.
// pg = t>>3 pair-group in [0,128), l = t&7 channel quad.
// red = [4 sets][128 pg][36] ; sets: 0=iA 1=jA 2=iB 3=jB.
// ---------------------------------------------------------------------------
template<bool WRITE_E, bool DO_PQ>
__global__ __launch_bounds__(1024) void rcf_node(
    const float* __restrict__ P, const float* __restrict__ Q,
    const float* __restrict__ e, const float* __restrict__ a,
    const float* __restrict__ sw_tail,   // sw + 480*CC : rows [w1 ; w2]
    const float* __restrict__ aiw, const float* __restrict__ aib,
    const float* __restrict__ ajw, const float* __restrict__ ajb,
    const float* __restrict__ ew, const float* __restrict__ eb,
    float* __restrict__ e_out,
    const float* __restrict__ xin, const float* __restrict__ nw,
    const float* __restrict__ nb,
    const float* __restrict__ sw2, const float* __restrict__ sb2,
    float* __restrict__ xout, float* __restrict__ Pout, float* __restrict__ Qout) {
    const int bid  = blockIdx.x;
    const int base = (bid & 7) * 50 + (bid >> 3) * 2;   // even
    const int t  = threadIdx.x;
    const int pg = t >> 3, l = t & 7, c0 = l * 4;

    __shared__ float red[4 * 128 * 36];   // 73.7 KB (overlaid by redn/red2 later)
    __shared__ float part[1024];
    __shared__ float vA[304], vB[304], xsA[240], xsB[240];
    __shared__ float eout_lds[2 * NN];
    float* redn = red;            // 2*16*240 = 7680 (overlays red)
    float* red2 = red;            // 2*16*64  = 2048 (overlays red)

    if (t < FF) {                 // stage both x-rows early
        vA[t] = xin[base * FF + t];
        vB[t] = xin[(base + 1) * FF + t];
    }

    // hoisted SHARED column gathers (one float2 line serves both rows)
    float2 er2[4], ak2[4];
    int kk[4];
    #pragma unroll
    for (int it = 0; it < 4; ++it) {
        const int off = it * 128 + pg;
        kk[it] = (off < NN) ? off : 0;
        er2[it] = *(const float2*)(e + kk[it] * NN + base);
        ak2[it] = *(const float2*)(a + kk[it] * NN + base);
    }

    float w1v[4], w2v[4], wiv[4], wjv[4], wev[4];
    *(float4*)w1v = *(const float4*)(sw_tail + c0);
    *(float4*)w2v = *(const float4*)(sw_tail + CC + c0);
    *(float4*)wiv = *(const float4*)(aiw + c0);
    *(float4*)wjv = *(const float4*)(ajw + c0);
    if (WRITE_E) *(float4*)wev = *(const float4*)(ew + c0);
    const float bi = aib[0], bj = ajb[0];
    const float be = WRITE_E ? eb[0] : 0.0f;

    #pragma unroll
    for (int rp = 0; rp < 2; ++rp) {
        const int b = base + rp;

        float Pb[4], Qb[4];
        *(float4*)Pb = *(const float4*)(P + b * CC + c0);
        *(float4*)Qb = *(const float4*)(Q + b * CC + c0);

        float acc_i[4] = {0, 0, 0, 0}, acc_j[4] = {0, 0, 0, 0};
        #pragma unroll
        for (int it = 0; it < 4; ++it) {
            const int off = it * 128 + pg;
            const bool valid = off < NN;
            const int k = kk[it];
            float Qk[4], Pk[4];
            *(float4*)Qk = *(const float4*)(Q + k * CC + c0);
            *(float4*)Pk = *(const float4*)(P + k * CC + c0);
            const float e_f  = e[b * NN + k];                    // coalesced
            const float a_bk = a[b * NN + k];                    // coalesced
            const float e_r  = rp ? er2[it].y : er2[it].x;       // shared gather
            const float a_kb = rp ? ak2[it].y : ak2[it].x;       // shared gather
            float sr[4], sc[4];
            #pragma unroll
            for (int q = 0; q < 4; ++q) {
                sr[q] = fmaxf(Pb[q] + Qk[q] + e_f * w1v[q] + e_r * w2v[q], 0.0f) * a_bk;
                sc[q] = fmaxf(Pk[q] + Qb[q] + e_r * w1v[q] + e_f * w2v[q], 0.0f) * a_kb;
            }
            float d_i = sr[0] * wiv[0] + sr[1] * wiv[1] + sr[2] * wiv[2] + sr[3] * wiv[3];
            float d_j = sc[0] * wjv[0] + sc[1] * wjv[1] + sc[2] * wjv[2] + sc[3] * wjv[3];
            float d_e = WRITE_E ? (sr[0] * wev[0] + sr[1] * wev[1] + sr[2] * wev[2] + sr[3] * wev[3]) : 0.0f;
            #pragma unroll
            for (int m = 1; m < 8; m <<= 1) {
                d_i += __shfl_xor(d_i, m);
                d_j += __shfl_xor(d_j, m);
                if (WRITE_E) d_e += __shfl_xor(d_e, m);
            }
            const float gi = valid ? __fdividef(1.0f, 1.0f + __expf(-(d_i + bi))) : 0.0f;
            const float gj = valid ? __fdividef(1.0f, 1.0f + __expf(-(d_j + bj))) : 0.0f;
            #pragma unroll
            for (int q = 0; q < 4; ++q) {
                acc_i[q] += gi * sr[q];
                acc_j[q] += gj * sc[q];
            }
            if (WRITE_E && l == 0 && valid) eout_lds[rp * NN + k] = d_e + be;
        }
        // publish this row's partials to LDS — NO barrier yet
        #pragma unroll
        for (int q = 0; q < 4; ++q) {
            red[((rp * 2 + 0) * 128 + pg) * 36 + c0 + q] = acc_i[q];
            red[((rp * 2 + 1) * 128 + pg) * 36 + c0 + q] = acc_j[q];
        }
    }
    __syncthreads();   // sync #1: all 4 sets published

    // coalesced e_out store (rows base, base+1 contiguous in memory)
    if (WRITE_E && t < 2 * NN) e_out[base * NN + t] = eout_lds[t];

    // combined stage-1: 1024 threads, set = t>>8 (0=iA 1=jA 2=iB 3=jB)
    {
        const int c = t & 31, sg = (t >> 5) & 7, set = t >> 8;
        float s = 0.0f;
        #pragma unroll
        for (int g2 = sg * 16; g2 < sg * 16 + 16; ++g2)
            s += red[(set * 128 + g2) * 36 + c];
        part[t] = s;
    }
    __syncthreads();   // sync #2

    // stage-2: 128 threads -> vA/vB[240..303]
    if (t < 128) {
        const int set = t >> 5, c = t & 31;
        float s = 0.0f;
        #pragma unroll
        for (int sg = 0; sg < 8; ++sg) s += part[set * 256 + sg * 32 + c];
        float* vdst = (set < 2) ? vA : vB;
        vdst[FF + (set & 1) * CC + c] = s;
    }
    __syncthreads();   // sync #3

    // ---- node tail for BOTH rows: nw read once per block ----
    {
        const int fg = t % 60, h = t / 60;   // h in [0,16), 19 k each
        if (t < 960) {
            const int f0 = fg * 4;
            float4 aA = make_float4(0.f, 0.f, 0.f, 0.f);
            float4 aB = make_float4(0.f, 0.f, 0.f, 0.f);
            const int k0 = h * 19;
            #pragma unroll
            for (int k = k0; k < k0 + 19; ++k) {
                const float4 w = *(const float4*)(nw + k * FF + f0);
                const float va = vA[k], vb = vB[k];
                aA.x += va * w.x; aA.y += va * w.y; aA.z += va * w.z; aA.w += va * w.w;
                aB.x += vb * w.x; aB.y += vb * w.y; aB.z += vb * w.z; aB.w += vb * w.w;
            }
            *(float4*)(redn + h * 240 + f0)        = aA;
            *(float4*)(redn + 3840 + h * 240 + f0) = aB;
        }
    }
    __syncthreads();
    if (t < FF) {
        float rA = nb[t], rB = nb[t];
        #pragma unroll
        for (int h = 0; h < 16; ++h) {
            rA += redn[h * 240 + t];
            rB += redn[3840 + h * 240 + t];
        }
        xout[base * FF + t]       = rA;
        xout[(base + 1) * FF + t] = rB;
        xsA[t] = rA;
        xsB[t] = rB;
    }
    if (DO_PQ) {
        __syncthreads();
        const int c = t & 31, isQ = (t >> 5) & 1, g = t >> 6;   // g in [0,16)
        const float* wb = sw2 + (isQ ? FF * CC : 0) + c;
        const float bias = (!isQ && g == 0) ? sb2[c] : 0.0f;
        float accA = bias, accB = bias;
        const int f0 = g * 15;
        #pragma unroll
        for (int f = f0; f < f0 + 15; ++f) {
            const float w = wb[f * CC];
            accA += xsA[f] * w;
            accB += xsB[f] * w;
        }
        red2[g * 64 + (t & 63)]        = accA;
        red2[1024 + g * 64 + (t & 63)] = accB;
        __syncthreads();
        if (t < 128) {
            const int row = t >> 6, slot = t & 63;
            float s = 0.0f;
            #pragma unroll
            for (int g2 = 0; g2 < 16; ++g2) s += red2[row * 1024 + g2 * 64 + slot];
            const int bb = base + row;
            if (slot >= 32) Qout[bb * CC + (slot & 31)] = s;
            else            Pout[bb * CC + slot] = s;
        }
    }
}

// ---------------------------------------------------------------------------
// K4: in-block split-K dense (proven). 1024 threads = 4 f-chunks x 256
// l-lanes; 60 loads/thread; partials reduced through LDS.
// grid = (50, 6), block 1024.
// ---------------------------------------------------------------------------
__global__ __launch_bounds__(1024) void dense_kernel(
    const float* __restrict__ x, const float* __restrict__ dw,
    const float* __restrict__ db, float* __restrict__ out) {
    const int i0 = blockIdx.x * 8;
    const int t  = threadIdx.x;
    const int l  = t & 255;          // l-lane
    const int fs = t >> 8;           // f-chunk 0..3
    const int gl = blockIdx.y * 256 + l;
    __shared__ float xs[8 * FF];     // 1920
    __shared__ float red[32 * 256];  // 8192
    for (int idx = t; idx < 8 * FF; idx += 1024) {
        const int r = idx / FF, f = idx - r * FF;
        xs[r * FF + f] = x[(i0 + r) * FF + f];
    }
    __syncthreads();
    float acc[8] = {0, 0, 0, 0, 0, 0, 0, 0};
    if (gl < LL) {
        const int f0 = fs * 60;
        #pragma unroll 4
        for (int f = f0; f < f0 + 60; ++f) {
            const float w = dw[f * LL + gl];
            #pragma unroll
            for (int r = 0; r < 8; ++r) acc[r] += xs[r * FF + f] * w;
        }
    }
    #pragma unroll
    for (int r = 0; r < 8; ++r) red[(fs * 8 + r) * 256 + l] = acc[r];
    __syncthreads();
    if (gl < LL) {
        const int r2 = t >> 8;       // rows r2 and r2+4
        const float d = db[gl];
        #pragma unroll
        for (int rr = r2; rr < 8; rr += 4) {
            const float s = red[(0 + rr) * 256 + l] + red[(8 + rr) * 256 + l]
                          + red[(16 + rr) * 256 + l] + red[(24 + rr) * 256 + l];
            out[(i0 + rr) * LL + gl] = d + s;
        }
    }
}

extern "C" void kernel_launch(void* const* d_in, const int* in_sizes, int n_in,
                              void* d_out, int out_size, void* d_ws, size_t ws_size,
                              hipStream_t stream) {
    const float* x  = (const float*)d_in[0];
    const float* a  = (const float*)d_in[1];
    const float* e0 = (const float*)d_in[2];

    const float* c1_sw  = (const float*)d_in[3];
    const float* c1_sb  = (const float*)d_in[4];
    const float* c1_aiw = (const float*)d_in[5];
    const float* c1_aib = (const float*)d_in[6];
    const float* c1_ajw = (const float*)d_in[7];
    const float* c1_ajb = (const float*)d_in[8];
    const float* c1_nw  = (const float*)d_in[9];
    const float* c1_nb  = (const float*)d_in[10];
    const float* c1_ew  = (const float*)d_in[11];
    const float* c1_eb  = (const float*)d_in[12];

    const float* c2_sw  = (const float*)d_in[13];
    const float* c2_sb  = (const float*)d_in[14];
    const float* c2_aiw = (const float*)d_in[15];
    const float* c2_aib = (const float*)d_in[16];
    const float* c2_ajw = (const float*)d_in[17];
    const float* c2_ajb = (const float*)d_in[18];
    const float* c2_nw  = (const float*)d_in[19];
    const float* c2_nb  = (const float*)d_in[20];
    // d_in[21]/d_in[22] (c2_ew/c2_eb): layer-2 edge output is dead code
    const float* dw = (const float*)d_in[23];
    const float* db = (const float*)d_in[24];

    float* ws = (float*)d_ws;
    float* P1 = ws;                 // 12800
    float* Q1 = ws + 12800;         // 12800
    float* P2 = ws + 25600;         // 12800
    float* Q2 = ws + 38400;         // 12800
    float* x1 = ws + 51200;         // 96000
    float* x2 = ws + 147200;        // 96000
    float* e1 = ws + 243200;        // 160000

    float* out = (float*)d_out;

    // K1: layer-1 P/Q projection (1 row/block)
    pq_kernel<<<NN, 256, 0, stream>>>(x, c1_sw, c1_sb, P1, Q1);

    // K2: layer-1 rcf + node model + layer-2 P/Q (combined reduction)
    rcf_node<true, true><<<NN / 2, 1024, 0, stream>>>(
        P1, Q1, e0, a, c1_sw + 480 * CC,
        c1_aiw, c1_aib, c1_ajw, c1_ajb, c1_ew, c1_eb, e1,
        x, c1_nw, c1_nb, c2_sw, c2_sb, x1, P2, Q2);

    // K3: layer-2 rcf + node model (no e_out, no next PQ)
    rcf_node<false, false><<<NN / 2, 1024, 0, stream>>>(
        P2, Q2, e1, a, c2_sw + 480 * CC,
        c2_aiw, c2_aib, c2_ajw, c2_ajb, nullptr, nullptr, nullptr,
        x1, c2_nw, c2_nb, nullptr, nullptr, x2, nullptr, nullptr);

    // K4: final dense (in-block split-K)
    dense_kernel<<<dim3(NN / 8, 6), 1024, 0, stream>>>(x2, dw, db, out);
}